// Round 2
// baseline (438.899 us; speedup 1.0000x reference)
//
#include <hip/hip_runtime.h>
#include <hip/hip_cooperative_groups.h>

namespace cg = cooperative_groups;

typedef __bf16 bf16;
typedef __bf16 bf16x8 __attribute__((ext_vector_type(8)));
typedef float f32x16 __attribute__((ext_vector_type(16)));

#define B_ROWS 16384
#define N_DIM  4096
#define K_DIM  128

// ---------------------------------------------------------------------------
// Single cooperative kernel. 512 blocks x 256 threads, 2 blocks/CU.
// Phase 1: each block transposes 8 V-rows (4 KB) -> Ut (bf16) + fp32 column
//          partial sums into spart[512][128].  grid.sync().
// Phase 2: pair-processed main loop (2 K-tiles per barrier, 4-slot xs ring,
//          exact vmcnt(12) counted waits).  Epilogue folds the snorm
//          reduction (512-wide spart) + linear/term2 combine.
// ---------------------------------------------------------------------------
__global__ __launch_bounds__(256, 2) void fm_fused(const float* __restrict__ x,
                                                   const float* __restrict__ W,
                                                   const float* __restrict__ bptr,
                                                   const float* __restrict__ V,
                                                   float* __restrict__ spart,
                                                   bf16* __restrict__ Ut,
                                                   float* __restrict__ out) {
    __shared__ bf16  xs[4][32 * 72];      // 4-slot ring, padded x tiles (18.4 KB)
    __shared__ bf16  us[2][128 * 64];     // Ut tiles, DMA dest (32 KB)
    __shared__ float redxs[256];
    __shared__ float redxw[256];
    __shared__ float rowsq[4 * 32];
    __shared__ float sp2[256];
    __shared__ float snred[2];
    __shared__ float spf[8 * 128];        // phase-1 fp32 tile (4 KB)
    __shared__ bf16  tb[128 * 10];        // phase-1 transposed bf16 tile

    const int t    = threadIdx.x;
    const int wave = t >> 6;
    const int lane = t & 63;
    const int l31  = lane & 31;
    const int h    = lane >> 5;
    const int r0   = blockIdx.x * 32;

    // ---------------- Phase 1: V transpose + column partials ----------------
    {
        const int vbase = blockIdx.x * 8 * 128;          // 8 rows of V
        float4 v4 = *(const float4*)(V + vbase + t * 4);
        const int r  = t >> 5;                           // 0..7
        const int c0 = (t & 31) * 4;                     // 0..124
        spf[r * 128 + c0 + 0] = v4.x;
        spf[r * 128 + c0 + 1] = v4.y;
        spf[r * 128 + c0 + 2] = v4.z;
        spf[r * 128 + c0 + 3] = v4.w;
        tb[(c0 + 0) * 10 + r] = (bf16)v4.x;
        tb[(c0 + 1) * 10 + r] = (bf16)v4.y;
        tb[(c0 + 2) * 10 + r] = (bf16)v4.z;
        tb[(c0 + 3) * 10 + r] = (bf16)v4.w;
        __syncthreads();
        if (t < 128) {
            float sv = 0.f;
#pragma unroll
            for (int r2 = 0; r2 < 8; ++r2) sv += spf[r2 * 128 + t];
            spart[(size_t)blockIdx.x * 128 + t] = sv;
            union { bf16 hv[8]; uint4 u; } pk;
#pragma unroll
            for (int k = 0; k < 8; ++k) pk.hv[k] = tb[t * 10 + k];
            *(uint4*)(Ut + (size_t)t * N_DIM + blockIdx.x * 8) = pk.u;
        }
    }
    cg::this_grid().sync();

    // ---------------- Phase 2: main loop ----------------
    const int srow = t >> 3;              // 0..31 x row
    const int scg  = t & 7;               // 0..7 chunk of 8 floats

    f32x16 acc;
#pragma unroll
    for (int i = 0; i < 16; ++i) acc[i] = 0.f;

    float xsum_acc = 0.f, xw_acc = 0.f;
    const float* xrow = x + (size_t)(r0 + srow) * N_DIM + scg * 8;
    const float* wrow = W + scg * 8;
    const bf16* ub = Ut + (size_t)(wave * 32 + (lane >> 3)) * N_DIM + (lane & 7) * 8;

    // prologue: DMA tiles 0,1 ; regs tiles 0,1
#pragma unroll
    for (int j = 0; j < 4; ++j) {
        __builtin_amdgcn_global_load_lds(
            (const __attribute__((address_space(1))) void*)(ub + (size_t)j * 8 * N_DIM),
            (__attribute__((address_space(3))) void*)&us[0][(wave * 32 + j * 8) * 64],
            16, 0, 0);
    }
#pragma unroll
    for (int j = 0; j < 4; ++j) {
        __builtin_amdgcn_global_load_lds(
            (const __attribute__((address_space(1))) void*)(ub + (size_t)j * 8 * N_DIM + 64),
            (__attribute__((address_space(3))) void*)&us[1][(wave * 32 + j * 8) * 64],
            16, 0, 0);
    }
    __builtin_amdgcn_sched_barrier(0);
    float4 a0 = *(const float4*)(xrow);
    float4 a1 = *(const float4*)(xrow + 4);
    float4 w0 = *(const float4*)(wrow);
    float4 w1 = *(const float4*)(wrow + 4);
    float4 b0 = *(const float4*)(xrow + 64);
    float4 b1 = *(const float4*)(xrow + 68);
    float4 v0 = *(const float4*)(wrow + 64);
    float4 v1 = *(const float4*)(wrow + 68);
    __builtin_amdgcn_sched_barrier(0);

    for (int p = 0; p < 32; ++p) {
        const int i0 = 2 * p;
        const int s0 = i0 & 3, s1 = (i0 + 1) & 3;
        const int kb2 = ((i0 + 2 < 64) ? (i0 + 2) : 0) * 64;
        const int kb3 = ((i0 + 3 < 64) ? (i0 + 3) : 0) * 64;

        // ---- store x regs tiles i0, i0+1 into ring slots s0, s1 ----
        bf16x8 xb;
        xb[0] = (bf16)a0.x; xb[1] = (bf16)a0.y; xb[2] = (bf16)a0.z; xb[3] = (bf16)a0.w;
        xb[4] = (bf16)a1.x; xb[5] = (bf16)a1.y; xb[6] = (bf16)a1.z; xb[7] = (bf16)a1.w;
        *(bf16x8*)&xs[s0][srow * 72 + scg * 8] = xb;
        xb[0] = (bf16)b0.x; xb[1] = (bf16)b0.y; xb[2] = (bf16)b0.z; xb[3] = (bf16)b0.w;
        xb[4] = (bf16)b1.x; xb[5] = (bf16)b1.y; xb[6] = (bf16)b1.z; xb[7] = (bf16)b1.w;
        *(bf16x8*)&xs[s1][srow * 72 + scg * 8] = xb;

        asm volatile("s_waitcnt lgkmcnt(0)" ::: "memory");
        __builtin_amdgcn_s_barrier();
        __builtin_amdgcn_sched_barrier(0);

        // ---- reg prefetch tiles i0+2, i0+3 (8 VMEM ops) ----
        float4 n0 = *(const float4*)(xrow + kb2);
        float4 n1 = *(const float4*)(xrow + kb2 + 4);
        float4 m0 = *(const float4*)(wrow + kb2);
        float4 m1 = *(const float4*)(wrow + kb2 + 4);
        float4 o0 = *(const float4*)(xrow + kb3);
        float4 o1 = *(const float4*)(xrow + kb3 + 4);
        float4 q0 = *(const float4*)(wrow + kb3);
        float4 q1 = *(const float4*)(wrow + kb3 + 4);
        __builtin_amdgcn_sched_barrier(0);

        // ---- fp32 side sums on tiles i0, i0+1 ----
        xsum_acc += (a0.x + a0.y + a0.z + a0.w) + (a1.x + a1.y + a1.z + a1.w)
                  + (b0.x + b0.y + b0.z + b0.w) + (b1.x + b1.y + b1.z + b1.w);
        xw_acc   += a0.x * w0.x + a0.y * w0.y + a0.z * w0.z + a0.w * w0.w
                  + a1.x * w1.x + a1.y * w1.y + a1.z * w1.z + a1.w * w1.w
                  + b0.x * v0.x + b0.y * v0.y + b0.z * v0.z + b0.w * v0.w
                  + b1.x * v1.x + b1.y * v1.y + b1.z * v1.z + b1.w * v1.w;
        __builtin_amdgcn_sched_barrier(0);

        // ---- wait DMA(i0) [12 newer VMEM in flight], MFMA even tile ----
        asm volatile("s_waitcnt vmcnt(12)" ::: "memory");
        __builtin_amdgcn_sched_barrier(0);
        __builtin_amdgcn_s_setprio(1);
#pragma unroll
        for (int ks = 0; ks < 64; ks += 16) {
            bf16x8 af  = *(const bf16x8*)&xs[s0][l31 * 72 + ks + h * 8];
            bf16x8 bfv = *(const bf16x8*)&us[0][(wave * 32 + l31) * 64 + ks + h * 8];
            acc = __builtin_amdgcn_mfma_f32_32x32x16_bf16(af, bfv, acc, 0, 0, 0);
        }
        __builtin_amdgcn_s_setprio(0);
        __builtin_amdgcn_sched_barrier(0);
        // DMA tile i0+2 -> us[0] (after its reads)
#pragma unroll
        for (int j = 0; j < 4; ++j) {
            __builtin_amdgcn_global_load_lds(
                (const __attribute__((address_space(1))) void*)(ub + (size_t)j * 8 * N_DIM + kb2),
                (__attribute__((address_space(3))) void*)&us[0][(wave * 32 + j * 8) * 64],
                16, 0, 0);
        }
        __builtin_amdgcn_sched_barrier(0);

        // ---- wait DMA(i0+1), MFMA odd tile ----
        asm volatile("s_waitcnt vmcnt(12)" ::: "memory");
        __builtin_amdgcn_sched_barrier(0);
        __builtin_amdgcn_s_setprio(1);
#pragma unroll
        for (int ks = 0; ks < 64; ks += 16) {
            bf16x8 af  = *(const bf16x8*)&xs[s1][l31 * 72 + ks + h * 8];
            bf16x8 bfv = *(const bf16x8*)&us[1][(wave * 32 + l31) * 64 + ks + h * 8];
            acc = __builtin_amdgcn_mfma_f32_32x32x16_bf16(af, bfv, acc, 0, 0, 0);
        }
        __builtin_amdgcn_s_setprio(0);
        __builtin_amdgcn_sched_barrier(0);
        // DMA tile i0+3 -> us[1]
#pragma unroll
        for (int j = 0; j < 4; ++j) {
            __builtin_amdgcn_global_load_lds(
                (const __attribute__((address_space(1))) void*)(ub + (size_t)j * 8 * N_DIM + kb3),
                (__attribute__((address_space(3))) void*)&us[1][(wave * 32 + j * 8) * 64],
                16, 0, 0);
        }
        __builtin_amdgcn_sched_barrier(0);

        a0 = n0; a1 = n1; w0 = m0; w1 = m1;
        b0 = o0; b1 = o1; v0 = q0; v1 = q1;
    }

    // ---- epilogue ----
    __syncthreads();   // full drain (incl. tail DMAs)
    redxs[t] = xsum_acc;
    redxw[t] = xw_acc;

    // per-row sum of squares over this wave's 32 cols.
    // C/D layout: col = lane&31, row = (reg&3) + 8*(reg>>2) + 4*(lane>>5)
#pragma unroll
    for (int r = 0; r < 16; ++r) {
        float s = acc[r] * acc[r];
        s += __shfl_xor(s, 1);
        s += __shfl_xor(s, 2);
        s += __shfl_xor(s, 4);
        s += __shfl_xor(s, 8);
        s += __shfl_xor(s, 16);
        if (l31 == 0) {
            int row = (r & 3) + 8 * (r >> 2) + 4 * h;
            rowsq[wave * 32 + row] = s;
        }
    }

    // snorm = ||V.sum(0)||^2 from spart[512][128] (L2-resident)
    {
        const int cc = t & 127, hh = t >> 7;
        float sv = 0.f;
#pragma unroll 8
        for (int i = 0; i < 256; ++i) sv += spart[(size_t)(hh * 256 + i) * 128 + cc];
        sp2[t] = sv;
    }
    __syncthreads();
    if (t < 128) {
        float s2 = sp2[t] + sp2[128 + t];
        float sq = s2 * s2;
#pragma unroll
        for (int m = 32; m >= 1; m >>= 1) sq += __shfl_down(sq, m, 64);
        if ((t & 63) == 0) snred[t >> 6] = sq;
    }
    __syncthreads();

    if (t < 32) {
        float xsum = 0.f, xw = 0.f;
#pragma unroll
        for (int g = 0; g < 8; ++g) { xsum += redxs[t * 8 + g]; xw += redxw[t * 8 + g]; }
        float sq = rowsq[t] + rowsq[32 + t] + rowsq[64 + t] + rowsq[96 + t];
        float snorm = snred[0] + snred[1];
        float bv = bptr[0];
        out[r0 + t] = bv + xw + 0.5f * sq - 0.5f * xsum * xsum * snorm;
    }
}

// ---------------------------------------------------------------------------
extern "C" void kernel_launch(void* const* d_in, const int* in_sizes, int n_in,
                              void* d_out, int out_size, void* d_ws, size_t ws_size,
                              hipStream_t stream) {
    const float* x  = (const float*)d_in[0];
    const float* W  = (const float*)d_in[1];
    const float* bp = (const float*)d_in[2];
    const float* V  = (const float*)d_in[3];
    float* out = (float*)d_out;

    char* ws = (char*)d_ws;
    float* spart = (float*)(ws + 1024);             // 512*128*4 = 256 KB
    bf16*  Ut    = (bf16*)(ws + 1024 + 262144);     // 1 MB

    void* args[] = { (void*)&x, (void*)&W, (void*)&bp, (void*)&V,
                     (void*)&spart, (void*)&Ut, (void*)&out };
    hipLaunchCooperativeKernel((void*)fm_fused, dim3(512), dim3(256), args, 0, stream);
}

// Round 3
// 394.181 us; speedup vs baseline: 1.1134x; 1.1134x over previous
//
#include <hip/hip_runtime.h>

typedef __bf16 bf16;
typedef __bf16 bf16x8 __attribute__((ext_vector_type(8)));
typedef float f32x16 __attribute__((ext_vector_type(16)));

#define B_ROWS 16384
#define N_DIM  4096
#define K_DIM  128

// ---------------------------------------------------------------------------
// Kernel 1: transpose V (4096x128 f32) -> Ut (128x4096 bf16), fused with
// per-column partial sums (for s = V.sum(0)).  (unchanged, proven)
// ---------------------------------------------------------------------------
__global__ __launch_bounds__(256) void prep_kernel(const float* __restrict__ V,
                                                   float* __restrict__ spart,
                                                   bf16* __restrict__ Ut) {
    __shared__ bf16 tile[128 * 136];
    __shared__ float sp[256];
    const int t = threadIdx.x;
    const int jbase = blockIdx.x * 128;
    const int c  = t & 127;
    const int j0 = t >> 7;

    float sacc = 0.f;
#pragma unroll 8
    for (int i = 0; i < 64; ++i) {
        int j = j0 + 2 * i;
        float v = V[(size_t)(jbase + j) * K_DIM + c];
        sacc += v;
        tile[c * 136 + j] = (bf16)v;
    }
    sp[t] = sacc;
    __syncthreads();
    if (t < 128) spart[blockIdx.x * 128 + t] = sp[t] + sp[t + 128];

    const int col = t >> 1, half = t & 1;
#pragma unroll
    for (int i = 0; i < 4; ++i) {
        uint4 d = *(const uint4*)&tile[col * 136 + half * 64 + i * 16];
        *(uint4*)&Ut[(size_t)col * N_DIM + jbase + half * 64 + i * 16] = d;
    }
}

// ---------------------------------------------------------------------------
// Kernel 2 (main): BM=32 rows/block, 512 blocks, 256 threads = 4 waves.
// T2 LDS XOR-swizzle (both-sides, rule #21):
//   us: DMA dest is linear; the GLOBAL source is pre-swizzled per-lane
//       (src chunk = (lane&7) ^ (lane>>3), since dest row&7 == lane>>3),
//       and ds_read applies chunk ^= (row&7).  Kills the 32-way conflict
//       (row stride 128B put all 32 lanes on the same 4 banks).
//   xs: plain ds_write store side swizzled (chunk = scg ^ (srow&7)),
//       read side matches; pad dropped (stride 64, conflict-free).
// Loop/waits identical to round-1 (counted vmcnt(12), 1 barrier/iter).
// snorm = ||V.sum(0)||^2 folded into epilogue.
// ---------------------------------------------------------------------------
__global__ __launch_bounds__(256, 2) void fm_main(const float* __restrict__ x,
                                                  const float* __restrict__ W,
                                                  const float* __restrict__ bptr,
                                                  const bf16* __restrict__ Ut,
                                                  const float* __restrict__ spart,
                                                  float* __restrict__ out) {
    __shared__ bf16  xs[2][32 * 64];      // swizzled x tile, bf16 (8 KB)
    __shared__ bf16  us[2][128 * 64];     // swizzled Ut tile, DMA dest (32 KB)
    __shared__ float redxs[256];
    __shared__ float redxw[256];
    __shared__ float rowsq[4 * 32];
    __shared__ float snred[2];

    const int t    = threadIdx.x;
    const int wave = t >> 6;
    const int lane = t & 63;
    const int l31  = lane & 31;
    const int h    = lane >> 5;
    const int r0   = blockIdx.x * 32;

    const int srow = t >> 3;              // 0..31 x row
    const int scg  = t & 7;               // 0..7 chunk of 8 floats
    const int sxch = (scg ^ (srow & 7));  // swizzled xs chunk for this thread

    f32x16 acc;
#pragma unroll
    for (int i = 0; i < 16; ++i) acc[i] = 0.f;

    float xsum_acc = 0.f, xw_acc = 0.f;
    const float* xrow = x + (size_t)(r0 + srow) * N_DIM + scg * 8;
    const float* wrow = W + scg * 8;
    // DMA source, pre-swizzled: lane covers dest (row_local = lane>>3,
    // phys chunk = lane&7); logical source chunk = (lane&7) ^ (lane>>3).
    const bf16* ub = Ut + (size_t)(wave * 32 + (lane >> 3)) * N_DIM
                        + (size_t)(((lane & 7) ^ (lane >> 3)) * 8);

    // ---- prologue: DMA tile 0; register tiles 0 and 1 ----
#pragma unroll
    for (int j = 0; j < 4; ++j) {
        __builtin_amdgcn_global_load_lds(
            (const __attribute__((address_space(1))) void*)(ub + (size_t)j * 8 * N_DIM),
            (__attribute__((address_space(3))) void*)&us[0][(wave * 32 + j * 8) * 64],
            16, 0, 0);
    }
    float4 a0 = *(const float4*)(xrow);
    float4 a1 = *(const float4*)(xrow + 4);
    float4 w0 = *(const float4*)(wrow);
    float4 w1 = *(const float4*)(wrow + 4);
    float4 b0 = *(const float4*)(xrow + 64);
    float4 b1 = *(const float4*)(xrow + 68);
    float4 v0 = *(const float4*)(wrow + 64);
    float4 v1 = *(const float4*)(wrow + 68);

    for (int it = 0; it < 64; ++it) {
        const int bsel = it & 1;
        const int kb1 = (it < 63) ? (it + 1) * 64 : 0;  // clamp: harmless reload
        const int kb2 = (it < 62) ? (it + 2) * 64 : 0;

        // ---- store x regs (tile it) into xs[bsel], swizzled chunk ----
        bf16x8 xb;
        xb[0] = (bf16)a0.x; xb[1] = (bf16)a0.y; xb[2] = (bf16)a0.z; xb[3] = (bf16)a0.w;
        xb[4] = (bf16)a1.x; xb[5] = (bf16)a1.y; xb[6] = (bf16)a1.z; xb[7] = (bf16)a1.w;
        *(bf16x8*)&xs[bsel][srow * 64 + sxch * 8] = xb;

        // xs[bsel] visible to all waves; no vmcnt drain here (counted wait below)
        asm volatile("s_waitcnt lgkmcnt(0)" ::: "memory");
        __builtin_amdgcn_s_barrier();
        __builtin_amdgcn_sched_barrier(0);

        // ---- issue DMA tile it+1 -> us[bsel^1] (oldest in vmcnt queue) ----
#pragma unroll
        for (int j = 0; j < 4; ++j) {
            __builtin_amdgcn_global_load_lds(
                (const __attribute__((address_space(1))) void*)(ub + (size_t)j * 8 * N_DIM + kb1),
                (__attribute__((address_space(3))) void*)&us[bsel ^ 1][(wave * 32 + j * 8) * 64],
                16, 0, 0);
        }
        __builtin_amdgcn_sched_barrier(0);   // pin DMA-before-loads issue order

        // ---- 2-deep register prefetch: tile it+2 ----
        float4 n0 = *(const float4*)(xrow + kb2);
        float4 n1 = *(const float4*)(xrow + kb2 + 4);
        float4 m0 = *(const float4*)(wrow + kb2);
        float4 m1 = *(const float4*)(wrow + kb2 + 4);

        // ---- exact fp32 side computations on tile-it regs ----
        xsum_acc += (a0.x + a0.y + a0.z + a0.w) + (a1.x + a1.y + a1.z + a1.w);
        xw_acc   += a0.x * w0.x + a0.y * w0.y + a0.z * w0.z + a0.w * w0.w
                  + a1.x * w1.x + a1.y * w1.y + a1.z * w1.z + a1.w * w1.w;

        // retire exactly the us[bsel] DMA (12 newer VMEM ops stay in flight)
        asm volatile("s_waitcnt vmcnt(12)" ::: "memory");
        __builtin_amdgcn_sched_barrier(0);

        // ---- MFMA on buffer bsel (reads apply the matching XOR) ----
        __builtin_amdgcn_s_setprio(1);
#pragma unroll
        for (int ks = 0; ks < 64; ks += 16) {
            const int ch = (ks >> 3) + h;            // logical chunk 0..7
            const int cx = (ch ^ (l31 & 7)) * 8;     // swizzled element offset
            bf16x8 af  = *(const bf16x8*)&xs[bsel][l31 * 64 + cx];
            bf16x8 bfv = *(const bf16x8*)&us[bsel][(wave * 32 + l31) * 64 + cx];
            acc = __builtin_amdgcn_mfma_f32_32x32x16_bf16(af, bfv, acc, 0, 0, 0);
        }
        __builtin_amdgcn_s_setprio(0);

        a0 = b0; a1 = b1; w0 = v0; w1 = v1;
        b0 = n0; b1 = n1; v0 = m0; v1 = m1;
    }

    // ---- epilogue ----
    redxs[t] = xsum_acc;
    redxw[t] = xw_acc;

    // per-row sum of squares over this wave's 32 cols.
    // C/D layout: col = lane&31, row = (reg&3) + 8*(reg>>2) + 4*(lane>>5)
#pragma unroll
    for (int r = 0; r < 16; ++r) {
        float s = acc[r] * acc[r];
        s += __shfl_xor(s, 1);
        s += __shfl_xor(s, 2);
        s += __shfl_xor(s, 4);
        s += __shfl_xor(s, 8);
        s += __shfl_xor(s, 16);
        if (l31 == 0) {
            int row = (r & 3) + 8 * (r >> 2) + 4 * h;
            rowsq[wave * 32 + row] = s;
        }
    }

    // snorm = ||V.sum(0)||^2 from spart (32x128, L2-resident), waves 0-1.
    if (t < 128) {
        float sv = 0.f;
#pragma unroll
        for (int bb = 0; bb < 32; ++bb) sv += spart[bb * 128 + t];
        float sq = sv * sv;
#pragma unroll
        for (int m = 32; m >= 1; m >>= 1) sq += __shfl_down(sq, m, 64);
        if ((t & 63) == 0) snred[t >> 6] = sq;
    }
    __syncthreads();   // also drains the dangling tail prefetch VMEM ops

    if (t < 32) {
        float xsum = 0.f, xw = 0.f;
#pragma unroll
        for (int g = 0; g < 8; ++g) { xsum += redxs[t * 8 + g]; xw += redxw[t * 8 + g]; }
        float sq = rowsq[t] + rowsq[32 + t] + rowsq[64 + t] + rowsq[96 + t];
        float snorm = snred[0] + snred[1];
        float bv = bptr[0];
        out[r0 + t] = bv + xw + 0.5f * sq - 0.5f * xsum * xsum * snorm;
    }
}

// ---------------------------------------------------------------------------
extern "C" void kernel_launch(void* const* d_in, const int* in_sizes, int n_in,
                              void* d_out, int out_size, void* d_ws, size_t ws_size,
                              hipStream_t stream) {
    const float* x  = (const float*)d_in[0];
    const float* W  = (const float*)d_in[1];
    const float* bp = (const float*)d_in[2];
    const float* V  = (const float*)d_in[3];
    float* out = (float*)d_out;

    char* ws = (char*)d_ws;
    float* spart = (float*)(ws + 1024);        // 16 KB
    bf16*  Ut    = (bf16*)(ws + 32768);        // 1 MB

    hipLaunchKernelGGL(prep_kernel, dim3(32), dim3(256), 0, stream, V, spart, Ut);
    hipLaunchKernelGGL(fm_main, dim3(512), dim3(256), 0, stream, x, W, bp, Ut, spart, out);
}

// Round 4
// 371.552 us; speedup vs baseline: 1.1813x; 1.0609x over previous
//
#include <hip/hip_runtime.h>

typedef __bf16 bf16;
typedef __bf16 bf16x8 __attribute__((ext_vector_type(8)));
typedef float f32x16 __attribute__((ext_vector_type(16)));

#define B_ROWS 16384
#define N_DIM  4096
#define K_DIM  128

// ---------------------------------------------------------------------------
// Kernel 1: transpose V (4096x128 f32) -> Ut (128x4096 bf16), fused with
// per-column partial sums (for s = V.sum(0)).  (unchanged, proven)
// ---------------------------------------------------------------------------
__global__ __launch_bounds__(256) void prep_kernel(const float* __restrict__ V,
                                                   float* __restrict__ spart,
                                                   bf16* __restrict__ Ut) {
    __shared__ bf16 tile[128 * 136];
    __shared__ float sp[256];
    const int t = threadIdx.x;
    const int jbase = blockIdx.x * 128;
    const int c  = t & 127;
    const int j0 = t >> 7;

    float sacc = 0.f;
#pragma unroll 8
    for (int i = 0; i < 64; ++i) {
        int j = j0 + 2 * i;
        float v = V[(size_t)(jbase + j) * K_DIM + c];
        sacc += v;
        tile[c * 136 + j] = (bf16)v;
    }
    sp[t] = sacc;
    __syncthreads();
    if (t < 128) spart[blockIdx.x * 128 + t] = sp[t] + sp[t + 128];

    const int col = t >> 1, half = t & 1;
#pragma unroll
    for (int i = 0; i < 4; ++i) {
        uint4 d = *(const uint4*)&tile[col * 136 + half * 64 + i * 16];
        *(uint4*)&Ut[(size_t)col * N_DIM + jbase + half * 64 + i * 16] = d;
    }
}

// ---------------------------------------------------------------------------
// Kernel 2 (main): BM=32, BK=128 (was 64): 32 iterations, 8 MFMA/iter.
// Rationale: all schedule variants measured ~114us with everything idle and
// latency-insensitive => fixed per-barrier-epoch cost dominates; double the
// work per epoch, halve epoch count (m97 reference: 16 MFMA/epoch).
// LDS = exactly 80 KB (2 blocks/CU): xs dbuf 16K + us dbuf 64K, carved from
// one pool; epilogue arrays alias xs region after a __syncthreads.
// Per-iter VMEM order: [x/W reg loads (8)] then [DMA (8)] so the compiler's
// in-order wait for regs never drains the DMAs; exact vmcnt(16) before MFMA
// retires only the current us buffer's DMA.
// 16-chunk XOR swizzle on xs and us (both-sides: pre-swizzled DMA source,
// matching XOR on ds_read/ds_write).
// ---------------------------------------------------------------------------
__global__ __launch_bounds__(256, 2) void fm_main(const float* __restrict__ x,
                                                  const float* __restrict__ W,
                                                  const float* __restrict__ bptr,
                                                  const bf16* __restrict__ Ut,
                                                  const float* __restrict__ spart,
                                                  float* __restrict__ out) {
    __shared__ __align__(16) char pool[81920];
    bf16* xs = (bf16*)pool;               // 2 bufs x 32 x 128 = 8192 elems (16 KB)
    bf16* us = (bf16*)(pool + 16384);     // 2 bufs x 128 x 128 = 32768 elems (64 KB)

    const int t    = threadIdx.x;
    const int wave = t >> 6;
    const int lane = t & 63;
    const int l31  = lane & 31;
    const int h    = lane >> 5;
    const int r0   = blockIdx.x * 32;

    const int srow = t >> 3;              // 0..31 x row
    const int scg  = t & 7;               // 0..7 chunk of 16 floats

    f32x16 acc;
#pragma unroll
    for (int i = 0; i < 16; ++i) acc[i] = 0.f;

    float xsum_acc = 0.f, xw_acc = 0.f;
    const float* xrow = x + (size_t)(r0 + srow) * N_DIM + scg * 16;
    const float* wrow = W + scg * 16;
    // DMA source rows/chunks: 8 instrs, instr j covers rows j*4+(lane>>4),
    // phys chunk lane&15 <- logical chunk (lane&15)^(row&15) (pre-swizzle).
    const int dr = lane >> 4;             // 0..3 row-sub within DMA group
    const int dc = lane & 15;             // phys chunk

    // ---- prologue: regs tile 0 FIRST (older than DMA(0) in vmcnt queue) ----
    float4 a0 = *(const float4*)(xrow);
    float4 a1 = *(const float4*)(xrow + 4);
    float4 a2 = *(const float4*)(xrow + 8);
    float4 a3 = *(const float4*)(xrow + 12);
    float4 w0 = *(const float4*)(wrow);
    float4 w1 = *(const float4*)(wrow + 4);
    float4 w2 = *(const float4*)(wrow + 8);
    float4 w3 = *(const float4*)(wrow + 12);
    __builtin_amdgcn_sched_barrier(0);
#pragma unroll
    for (int j = 0; j < 8; ++j) {
        const int rw = j * 4 + dr;                     // row within wave block
        const bf16* src = Ut + (size_t)(wave * 32 + rw) * N_DIM
                             + (size_t)((dc ^ (rw & 15)) * 8);
        __builtin_amdgcn_global_load_lds(
            (const __attribute__((address_space(1))) void*)src,
            (__attribute__((address_space(3))) void*)&us[(wave * 32 + j * 4) * 128],
            16, 0, 0);
    }
    __builtin_amdgcn_sched_barrier(0);

#pragma unroll 2
    for (int it = 0; it < 32; ++it) {
        const int bsel = it & 1;
        const int kb1 = ((it < 31) ? (it + 1) : 0) * 128;   // clamp: harmless

        // ---- store x regs (tile it) into xs[bsel], swizzled 16-B chunks ----
        bf16x8 xb;
        xb[0] = (bf16)a0.x; xb[1] = (bf16)a0.y; xb[2] = (bf16)a0.z; xb[3] = (bf16)a0.w;
        xb[4] = (bf16)a1.x; xb[5] = (bf16)a1.y; xb[6] = (bf16)a1.z; xb[7] = (bf16)a1.w;
        *(bf16x8*)&xs[bsel * 4096 + srow * 128 + (((scg * 2) ^ (srow & 15)) * 8)] = xb;
        xb[0] = (bf16)a2.x; xb[1] = (bf16)a2.y; xb[2] = (bf16)a2.z; xb[3] = (bf16)a2.w;
        xb[4] = (bf16)a3.x; xb[5] = (bf16)a3.y; xb[6] = (bf16)a3.z; xb[7] = (bf16)a3.w;
        *(bf16x8*)&xs[bsel * 4096 + srow * 128 + (((scg * 2 + 1) ^ (srow & 15)) * 8)] = xb;

        asm volatile("s_waitcnt lgkmcnt(0)" ::: "memory");
        __builtin_amdgcn_s_barrier();
        __builtin_amdgcn_sched_barrier(0);

        // ---- reg prefetch tile it+1 (8 VMEM, issued BEFORE the DMAs) ----
        float4 n0 = *(const float4*)(xrow + kb1);
        float4 n1 = *(const float4*)(xrow + kb1 + 4);
        float4 n2 = *(const float4*)(xrow + kb1 + 8);
        float4 n3 = *(const float4*)(xrow + kb1 + 12);
        float4 m0 = *(const float4*)(wrow + kb1);
        float4 m1 = *(const float4*)(wrow + kb1 + 4);
        float4 m2 = *(const float4*)(wrow + kb1 + 8);
        float4 m3 = *(const float4*)(wrow + kb1 + 12);
        __builtin_amdgcn_sched_barrier(0);

        // ---- DMA tile it+1 -> us[bsel^1] (8 instrs) ----
#pragma unroll
        for (int j = 0; j < 8; ++j) {
            const int rw = j * 4 + dr;
            const bf16* src = Ut + (size_t)(wave * 32 + rw) * N_DIM + kb1
                                 + (size_t)((dc ^ (rw & 15)) * 8);
            __builtin_amdgcn_global_load_lds(
                (const __attribute__((address_space(1))) void*)src,
                (__attribute__((address_space(3))) void*)&us[(bsel ^ 1) * 16384 + (wave * 32 + j * 4) * 128],
                16, 0, 0);
        }
        __builtin_amdgcn_sched_barrier(0);

        // ---- exact fp32 side sums on tile-it regs ----
        xsum_acc += (a0.x + a0.y + a0.z + a0.w) + (a1.x + a1.y + a1.z + a1.w)
                  + (a2.x + a2.y + a2.z + a2.w) + (a3.x + a3.y + a3.z + a3.w);
        xw_acc   += a0.x * w0.x + a0.y * w0.y + a0.z * w0.z + a0.w * w0.w
                  + a1.x * w1.x + a1.y * w1.y + a1.z * w1.z + a1.w * w1.w
                  + a2.x * w2.x + a2.y * w2.y + a2.z * w2.z + a2.w * w2.w
                  + a3.x * w3.x + a3.y * w3.y + a3.z * w3.z + a3.w * w3.w;

        // retire exactly DMA(it): 16 newer VMEM (8 regs + 8 DMA) stay in flight
        asm volatile("s_waitcnt vmcnt(16)" ::: "memory");
        __builtin_amdgcn_sched_barrier(0);

        // ---- 8 MFMA on buffer bsel (reads apply the matching XOR-16) ----
        __builtin_amdgcn_s_setprio(1);
#pragma unroll
        for (int ks = 0; ks < 128; ks += 16) {
            const int ch = (ks >> 3) + h;            // logical chunk 0..15
            const int cx = (ch ^ (l31 & 15)) * 8;    // swizzled element offset
            bf16x8 af  = *(const bf16x8*)&xs[bsel * 4096 + l31 * 128 + cx];
            bf16x8 bfv = *(const bf16x8*)&us[bsel * 16384 + (wave * 32 + l31) * 128 + cx];
            acc = __builtin_amdgcn_mfma_f32_32x32x16_bf16(af, bfv, acc, 0, 0, 0);
        }
        __builtin_amdgcn_s_setprio(0);

        a0 = n0; a1 = n1; a2 = n2; a3 = n3;
        w0 = m0; w1 = m1; w2 = m2; w3 = m3;
    }

    // ---- epilogue (aliases xs region of the pool; us untouched by aliases) ----
    __syncthreads();   // all waves done with LDS reads; drains tail VMEM
    float* redxs  = (float*)pool;           // 256 f
    float* redxw  = redxs + 256;            // 256 f
    float* rowsq  = redxw + 256;            // 128 f
    float* snred  = rowsq + 128;            // 2 f

    redxs[t] = xsum_acc;
    redxw[t] = xw_acc;

    // per-row sum of squares over this wave's 32 cols.
    // C/D layout: col = lane&31, row = (reg&3) + 8*(reg>>2) + 4*(lane>>5)
#pragma unroll
    for (int r = 0; r < 16; ++r) {
        float s = acc[r] * acc[r];
        s += __shfl_xor(s, 1);
        s += __shfl_xor(s, 2);
        s += __shfl_xor(s, 4);
        s += __shfl_xor(s, 8);
        s += __shfl_xor(s, 16);
        if (l31 == 0) {
            int row = (r & 3) + 8 * (r >> 2) + 4 * h;
            rowsq[wave * 32 + row] = s;
        }
    }

    // snorm = ||V.sum(0)||^2 from spart (32x128, L2-resident)
    if (t < 128) {
        float sv = 0.f;
#pragma unroll
        for (int bb = 0; bb < 32; ++bb) sv += spart[bb * 128 + t];
        float sq = sv * sv;
#pragma unroll
        for (int m = 32; m >= 1; m >>= 1) sq += __shfl_down(sq, m, 64);
        if ((t & 63) == 0) snred[t >> 6] = sq;
    }
    __syncthreads();

    if (t < 32) {
        float xsum = 0.f, xw = 0.f;
#pragma unroll
        for (int g = 0; g < 8; ++g) { xsum += redxs[t * 8 + g]; xw += redxw[t * 8 + g]; }
        float sq = rowsq[t] + rowsq[32 + t] + rowsq[64 + t] + rowsq[96 + t];
        float snorm = snred[0] + snred[1];
        float bv = bptr[0];
        out[r0 + t] = bv + xw + 0.5f * sq - 0.5f * xsum * xsum * snorm;
    }
}

// ---------------------------------------------------------------------------
extern "C" void kernel_launch(void* const* d_in, const int* in_sizes, int n_in,
                              void* d_out, int out_size, void* d_ws, size_t ws_size,
                              hipStream_t stream) {
    const float* x  = (const float*)d_in[0];
    const float* W  = (const float*)d_in[1];
    const float* bp = (const float*)d_in[2];
    const float* V  = (const float*)d_in[3];
    float* out = (float*)d_out;

    char* ws = (char*)d_ws;
    float* spart = (float*)(ws + 1024);        // 16 KB
    bf16*  Ut    = (bf16*)(ws + 32768);        // 1 MB

    hipLaunchKernelGGL(prep_kernel, dim3(32), dim3(256), 0, stream, V, spart, Ut);
    hipLaunchKernelGGL(fm_main, dim3(512), dim3(256), 0, stream, x, W, bp, Ut, spart, out);
}